// Round 1
// 570.067 us; speedup vs baseline: 1.0432x; 1.0432x over previous
//
#include <hip/hip_runtime.h>
#include <hip/hip_bf16.h>

typedef __bf16 bf16x4 __attribute__((ext_vector_type(4)));
typedef __bf16 bf16x8 __attribute__((ext_vector_type(8)));
typedef float  floatx4 __attribute__((ext_vector_type(4)));

#define AS1 __attribute__((address_space(1)))
#define AS3 __attribute__((address_space(3)))

// ---------------------------------------------------------------------------
// Prepass: fp32->bf16 (x) and int32->bf16 (wq), one launch.
// 4 elems/thread: one fully-contiguous 16B load + one 8B store per lane.
// ---------------------------------------------------------------------------
__global__ __launch_bounds__(256)
void cvt_both4(const float* __restrict__ xin, const int* __restrict__ win,
               __bf16* __restrict__ xout, __bf16* __restrict__ wout,
               int nx4, int nw4)
{
    int i = blockIdx.x * 256 + threadIdx.x;
    if (i < nx4) {
        float4 a = reinterpret_cast<const float4*>(xin)[i];
        bf16x4 h;
        h[0] = (__bf16)a.x; h[1] = (__bf16)a.y;
        h[2] = (__bf16)a.z; h[3] = (__bf16)a.w;
        reinterpret_cast<bf16x4*>(xout)[i] = h;
    } else {
        int j = i - nx4;
        if (j < nw4) {
            int4 a = reinterpret_cast<const int4*>(win)[j];
            bf16x4 h;
            h[0] = (__bf16)(float)a.x; h[1] = (__bf16)(float)a.y;
            h[2] = (__bf16)(float)a.z; h[3] = (__bf16)(float)a.w;
            reinterpret_cast<bf16x4*>(wout)[j] = h;
        }
    }
}

// ---------------------------------------------------------------------------
// GEMM v4: 256x256 tile, BK=64, 8 waves (2M x 4N), 4-phase K-tile schedule,
// counted vmcnt(4) (never drained in the main loop), setprio around MFMA,
// XOR-swizzled linear-dest global_load_lds (proven 0-conflict layout).
//
// Stage schedule (derived; buf c = kt&1, all quarters = 64 rows = 2 loads
// wait, = 1 load of 8KB per source call across 512 threads):
//   P0: stage A(kt+1) q1,q3 -> buf c^1   (overwrites A(kt-1) q1,q3: dead)
//       vmcnt(4); s_barrier              (publishes tile kt)
//       read all 8 B-frags + A-frags m0,m1 ; 16 MFMA ; barrier
//   P1: stage B(kt+1) q0..q3 -> buf c^1 ; A m2,m3 ; 16 MFMA ; barrier
//   P2: stage A(kt+2) q0,q2 -> buf c     (overwrites A(kt) q0,q2: dead
//       after P1 barrier — quadrant-by-m consumption) ; A m4,m5 ; 16 MFMA ; barrier
//   P3: A m6,m7 ; 16 MFMA ; barrier
// FIFO at each P0 wait: [.. B(kt)x4][A(kt+1)q02 x2][A(kt+1)q13 x2] -> vmcnt(4)
// holds uniformly from kt=0 given the prologue below.
// ---------------------------------------------------------------------------
#define BM2 256
#define BN2 256
#define BK2 64

template<int P>
__device__ __forceinline__ void phase_mfma(const __bf16* cA, const bf16x8 (&bfr)[4][2],
                                           floatx4 (&acc)[8][4],
                                           int wm, int lm, int kq, int sw)
{
    bf16x8 af[2][2];
#pragma unroll
    for (int ii = 0; ii < 2; ++ii)
#pragma unroll
        for (int h = 0; h < 2; ++h)
            af[ii][h] = *reinterpret_cast<const bf16x8*>(
                &cA[(wm + (2 * P + ii) * 16 + lm) * BK2 + ((kq + h * 4) ^ sw) * 8]);
    __builtin_amdgcn_s_setprio(1);
#pragma unroll
    for (int h = 0; h < 2; ++h)
#pragma unroll
        for (int ii = 0; ii < 2; ++ii)
#pragma unroll
            for (int j = 0; j < 4; ++j)
                acc[2 * P + ii][j] = __builtin_amdgcn_mfma_f32_16x16x32_bf16(
                                         af[ii][h], bfr[j][h], acc[2 * P + ii][j], 0, 0, 0);
    __builtin_amdgcn_s_setprio(0);
    asm volatile("s_barrier" ::: "memory");
}

__global__ __launch_bounds__(512)
void gemm_bf16_bt_8ph(const __bf16* __restrict__ A, const __bf16* __restrict__ B,
                      const float* __restrict__ scale, const float* __restrict__ bias,
                      float* __restrict__ Out, int M, int N, int K)
{
    __shared__ __bf16 sA[2][BM2 * BK2];   // 64 KB
    __shared__ __bf16 sB[2][BN2 * BK2];   // 64 KB

    const int tid  = threadIdx.x;
    const int wave = tid >> 6;
    const int lane = tid & 63;
    const int row0 = blockIdx.y * BM2;
    const int col0 = blockIdx.x * BN2;

    // --- staging geometry: one call = 512 thr x 16B = 8 KB = one 64-row quarter.
    // wave w covers rows [8w, 8w+8) of the quarter; lane l -> row l>>3,
    // stored blk l&7, fetched global blk (l&7)^(l>>3)  (LDS[row][b] = G[row][b^(row&7)]).
    const int sRow = lane >> 3;
    const int gBlk = (lane & 7) ^ sRow;
    const size_t aBase = (size_t)(row0 + wave * 8 + sRow) * K + gBlk * 8;
    const size_t bBase = (size_t)(col0 + wave * 8 + sRow) * K + gBlk * 8;
    const int ldsWOff = wave * 8 * BK2;

#define STAGE_A(buf, q, kt_) \
    __builtin_amdgcn_global_load_lds( \
        (const AS1 void*)(A + aBase + (size_t)(q) * 64 * K + (size_t)(kt_) * BK2), \
        (AS3 void*)&sA[(buf)][(q) * 64 * BK2 + ldsWOff], 16, 0, 0)
#define STAGE_B(buf, q, kt_) \
    __builtin_amdgcn_global_load_lds( \
        (const AS1 void*)(B + bBase + (size_t)(q) * 64 * K + (size_t)(kt_) * BK2), \
        (AS3 void*)&sB[(buf)][(q) * 64 * BK2 + ldsWOff], 16, 0, 0)

    // --- fragment geometry
    const int wm = (wave >> 2) * 128;     // 2 wave-rows
    const int wn = (wave & 3) * 64;       // 4 wave-cols
    const int lm = lane & 15;
    const int kq = lane >> 4;
    const int sw = lm & 7;                // row-derived XOR for frag reads

    floatx4 acc[8][4];
#pragma unroll
    for (int i = 0; i < 8; ++i)
#pragma unroll
        for (int j = 0; j < 4; ++j)
            acc[i][j] = (floatx4)0.0f;

    const int nt = K / BK2;

    // --- prologue: tile 0 fully + A(1) q0,q2  (emulates kt=-1 P2)
    STAGE_A(0, 0, 0); STAGE_A(0, 1, 0); STAGE_A(0, 2, 0); STAGE_A(0, 3, 0);
    STAGE_B(0, 0, 0); STAGE_B(0, 1, 0); STAGE_B(0, 2, 0); STAGE_B(0, 3, 0);
    STAGE_A(1, 0, 1); STAGE_A(1, 2, 1);

    for (int kt = 0; kt < nt; ++kt) {
        const int c  = kt & 1;
        const int n1 = (kt + 1 < nt) ? kt + 1 : 0;   // clamped phantoms keep
        const int n2 = (kt + 2 < nt) ? kt + 2 : 0;   // vmcnt math uniform
        const __bf16* cA = sA[c];
        const __bf16* cB = sB[c];

        // ---- P0 ----
        STAGE_A(c ^ 1, 1, n1); STAGE_A(c ^ 1, 3, n1);
        asm volatile("s_waitcnt vmcnt(4)" ::: "memory");   // publish tile kt
        asm volatile("s_barrier" ::: "memory");

        bf16x8 bfr[4][2];
#pragma unroll
        for (int j = 0; j < 4; ++j)
#pragma unroll
            for (int h = 0; h < 2; ++h)
                bfr[j][h] = *reinterpret_cast<const bf16x8*>(
                    &cB[(wn + j * 16 + lm) * BK2 + ((kq + h * 4) ^ sw) * 8]);
        phase_mfma<0>(cA, bfr, acc, wm, lm, kq, sw);

        // ---- P1 ----
        STAGE_B(c ^ 1, 0, n1); STAGE_B(c ^ 1, 1, n1);
        STAGE_B(c ^ 1, 2, n1); STAGE_B(c ^ 1, 3, n1);
        phase_mfma<1>(cA, bfr, acc, wm, lm, kq, sw);

        // ---- P2 ----
        STAGE_A(c, 0, n2); STAGE_A(c, 2, n2);
        phase_mfma<2>(cA, bfr, acc, wm, lm, kq, sw);

        // ---- P3 ----
        phase_mfma<3>(cA, bfr, acc, wm, lm, kq, sw);
    }

    // --- epilogue: C/D layout col=lane&15, row=(lane>>4)*4+reg (m89-verified)
#pragma unroll
    for (int j = 0; j < 4; ++j) {
        int n = col0 + wn + j * 16 + lm;
        float sc = scale[n];
        float bi = bias[n];
#pragma unroll
        for (int i = 0; i < 8; ++i) {
#pragma unroll
            for (int r = 0; r < 4; ++r) {
                int m = row0 + wm + i * 16 + kq * 4 + r;
                Out[(size_t)m * N + n] = sc * acc[i][j][r] + bi;
            }
        }
    }
#undef STAGE_A
#undef STAGE_B
}

// ---------------------------------------------------------------------------
// GEMM v3 (kept as fallback): 128x128 tile, BK=64, m97 structure.
// ---------------------------------------------------------------------------
#define BM 128
#define BN 128
#define BK 64

__global__ __launch_bounds__(256)
void gemm_bf16_bt(const __bf16* __restrict__ A, const __bf16* __restrict__ B,
                  const float* __restrict__ scale, const float* __restrict__ bias,
                  float* __restrict__ Out, int M, int N, int K)
{
    __shared__ __bf16 sA[BM * BK];
    __shared__ __bf16 sB[BN * BK];

    const int tid  = threadIdx.x;
    const int row0 = blockIdx.y * BM;
    const int col0 = blockIdx.x * BN;
    const int wave = tid >> 6;
    const int lane = tid & 63;

    const int sRow = lane >> 3;
    const int gBlk = (lane & 7) ^ sRow;
    size_t aOff[4], bOff[4];
    const __bf16* ldsA[4];
    const __bf16* ldsB[4];
#pragma unroll
    for (int q = 0; q < 4; ++q) {
        int r = wave * 32 + q * 8 + sRow;
        aOff[q] = (size_t)(row0 + r) * K + gBlk * 8;
        bOff[q] = (size_t)(col0 + r) * K + gBlk * 8;
        ldsA[q] = &sA[(wave * 32 + q * 8) * BK];
        ldsB[q] = &sB[(wave * 32 + q * 8) * BK];
    }

    const int wm = (wave >> 1) * 64;
    const int wn = (wave & 1) * 64;
    const int lm = lane & 15;
    const int kq = lane >> 4;
    const int sw = lm & 7;

    floatx4 acc[4][4];
#pragma unroll
    for (int i = 0; i < 4; ++i)
#pragma unroll
        for (int j = 0; j < 4; ++j)
            acc[i][j] = (floatx4)0.0f;

    for (int k0 = 0; k0 < K; k0 += BK) {
#pragma unroll
        for (int q = 0; q < 4; ++q) {
            __builtin_amdgcn_global_load_lds((const AS1 void*)(A + aOff[q] + k0),
                                             (AS3 void*)ldsA[q], 16, 0, 0);
            __builtin_amdgcn_global_load_lds((const AS1 void*)(B + bOff[q] + k0),
                                             (AS3 void*)ldsB[q], 16, 0, 0);
        }
        __syncthreads();

#pragma unroll
        for (int h = 0; h < 2; ++h) {
            const int blkA = (kq + h * 4);
            bf16x8 af[4], bfr[4];
#pragma unroll
            for (int i = 0; i < 4; ++i) {
                int row = wm + i * 16 + lm;
                af[i] = *reinterpret_cast<const bf16x8*>(
                            &sA[row * BK + (blkA ^ sw) * 8]);
            }
#pragma unroll
            for (int j = 0; j < 4; ++j) {
                int row = wn + j * 16 + lm;
                bfr[j] = *reinterpret_cast<const bf16x8*>(
                            &sB[row * BK + (blkA ^ sw) * 8]);
            }
#pragma unroll
            for (int i = 0; i < 4; ++i)
#pragma unroll
                for (int j = 0; j < 4; ++j)
                    acc[i][j] = __builtin_amdgcn_mfma_f32_16x16x32_bf16(
                                    af[i], bfr[j], acc[i][j], 0, 0, 0);
        }
        __syncthreads();
    }

#pragma unroll
    for (int j = 0; j < 4; ++j) {
        int n = col0 + wn + j * 16 + lm;
        float sc = scale[n];
        float bi = bias[n];
#pragma unroll
        for (int i = 0; i < 4; ++i) {
#pragma unroll
            for (int r = 0; r < 4; ++r) {
                int m = row0 + wm + i * 16 + kq * 4 + r;
                Out[(size_t)m * N + n] = sc * acc[i][j][r] + bi;
            }
        }
    }
}

// ---------------------------------------------------------------------------
// Fallback: fused conversion in staging, no workspace needed.
// ---------------------------------------------------------------------------
__global__ __launch_bounds__(256)
void fp4linear_gemm(const float* __restrict__ X, const int* __restrict__ W,
                    const float* __restrict__ scale, const float* __restrict__ bias,
                    float* __restrict__ Out, int M, int N, int K)
{
    __shared__ __bf16 sA[BM * 32];
    __shared__ __bf16 sB[BN * 32];

    const int tid  = threadIdx.x;
    const int row0 = blockIdx.y * BM;
    const int col0 = blockIdx.x * BN;
    const int wave = tid >> 6;
    const int lane = tid & 63;
    const int wm = (wave >> 1) * 64;
    const int wn = (wave & 1) * 64;
    const int lm = lane & 15;
    const int kq = lane >> 4;

    floatx4 acc[4][4];
#pragma unroll
    for (int i = 0; i < 4; ++i)
#pragma unroll
        for (int j = 0; j < 4; ++j)
            acc[i][j] = (floatx4)0.0f;

    for (int k0 = 0; k0 < K; k0 += 32) {
        float4 fa[4];
        int4   ib[4];
#pragma unroll
        for (int l = 0; l < 4; ++l) {
            int idx = tid + l * 256;
            int r = idx >> 3, c4 = idx & 7;
            fa[l] = *reinterpret_cast<const float4*>(
                        &X[(size_t)(row0 + r) * K + k0 + c4 * 4]);
        }
#pragma unroll
        for (int l = 0; l < 4; ++l) {
            int idx = tid + l * 256;
            int r = idx >> 3, c4 = idx & 7;
            ib[l] = *reinterpret_cast<const int4*>(
                        &W[(size_t)(col0 + r) * K + k0 + c4 * 4]);
        }
        __syncthreads();
#pragma unroll
        for (int l = 0; l < 4; ++l) {
            int idx = tid + l * 256;
            int r = idx >> 3, c4 = idx & 7;
            bf16x4 h;
            h[0] = (__bf16)fa[l].x; h[1] = (__bf16)fa[l].y;
            h[2] = (__bf16)fa[l].z; h[3] = (__bf16)fa[l].w;
            *reinterpret_cast<bf16x4*>(&sA[r * 32 + c4 * 4]) = h;
        }
#pragma unroll
        for (int l = 0; l < 4; ++l) {
            int idx = tid + l * 256;
            int r = idx >> 3, c4 = idx & 7;
            bf16x4 h;
            h[0] = (__bf16)(float)ib[l].x; h[1] = (__bf16)(float)ib[l].y;
            h[2] = (__bf16)(float)ib[l].z; h[3] = (__bf16)(float)ib[l].w;
            *reinterpret_cast<bf16x4*>(&sB[r * 32 + c4 * 4]) = h;
        }
        __syncthreads();

        bf16x8 af[4], bfr[4];
#pragma unroll
        for (int i = 0; i < 4; ++i)
            af[i] = *reinterpret_cast<const bf16x8*>(
                        &sA[(wm + i * 16 + lm) * 32 + kq * 8]);
#pragma unroll
        for (int j = 0; j < 4; ++j)
            bfr[j] = *reinterpret_cast<const bf16x8*>(
                        &sB[(wn + j * 16 + lm) * 32 + kq * 8]);
#pragma unroll
        for (int i = 0; i < 4; ++i)
#pragma unroll
            for (int j = 0; j < 4; ++j)
                acc[i][j] = __builtin_amdgcn_mfma_f32_16x16x32_bf16(
                                af[i], bfr[j], acc[i][j], 0, 0, 0);
    }

#pragma unroll
    for (int j = 0; j < 4; ++j) {
        int n = col0 + wn + j * 16 + lm;
        float sc = scale[n];
        float bi = bias[n];
#pragma unroll
        for (int i = 0; i < 4; ++i) {
#pragma unroll
            for (int r = 0; r < 4; ++r) {
                int m = row0 + wm + i * 16 + kq * 4 + r;
                Out[(size_t)m * N + n] = sc * acc[i][j][r] + bi;
            }
        }
    }
}

extern "C" void kernel_launch(void* const* d_in, const int* in_sizes, int n_in,
                              void* d_out, int out_size, void* d_ws, size_t ws_size,
                              hipStream_t stream) {
    const float* x     = (const float*)d_in[0];
    const int*   wq    = (const int*)d_in[1];
    const float* scale = (const float*)d_in[2];
    const float* bias  = (const float*)d_in[3];
    float* out = (float*)d_out;

    const int N = in_sizes[2];            // OUT = 4096
    const int K = in_sizes[1] / N;        // IN  = 4096
    const int M = in_sizes[0] / K;        // B*S = 8192

    const size_t xElems = (size_t)M * K;
    const size_t wElems = (size_t)N * K;
    const size_t need   = (xElems + wElems) * sizeof(__bf16);

    const bool cvt_ok = (ws_size >= need) && (xElems % 4 == 0) && (wElems % 4 == 0);

    if (cvt_ok && (M % BM2 == 0) && (N % BN2 == 0) && (K % BK2 == 0)) {
        __bf16* xb = (__bf16*)d_ws;
        __bf16* wb = xb + xElems;
        int nx4 = (int)(xElems / 4);
        int nw4 = (int)(wElems / 4);
        int total = nx4 + nw4;
        hipLaunchKernelGGL(cvt_both4, dim3((total + 255) / 256), dim3(256), 0, stream,
                           x, wq, xb, wb, nx4, nw4);
        hipLaunchKernelGGL(gemm_bf16_bt_8ph, dim3(N / BN2, M / BM2), dim3(512), 0, stream,
                           xb, wb, scale, bias, out, M, N, K);
    } else if (cvt_ok && (M % BM == 0) && (N % BN == 0) && (K % BK == 0)) {
        __bf16* xb = (__bf16*)d_ws;
        __bf16* wb = xb + xElems;
        int nx4 = (int)(xElems / 4);
        int nw4 = (int)(wElems / 4);
        int total = nx4 + nw4;
        hipLaunchKernelGGL(cvt_both4, dim3((total + 255) / 256), dim3(256), 0, stream,
                           x, wq, xb, wb, nx4, nw4);
        hipLaunchKernelGGL(gemm_bf16_bt, dim3(N / BN, M / BM), dim3(256), 0, stream,
                           xb, wb, scale, bias, out, M, N, K);
    } else {
        hipLaunchKernelGGL(fp4linear_gemm, dim3(N / BN, M / BM), dim3(256), 0, stream,
                           x, wq, scale, bias, out, M, N, K);
    }
}

// Round 2
// 545.319 us; speedup vs baseline: 1.0905x; 1.0454x over previous
//
#include <hip/hip_runtime.h>
#include <hip/hip_bf16.h>

typedef __bf16 bf16x4 __attribute__((ext_vector_type(4)));
typedef __bf16 bf16x8 __attribute__((ext_vector_type(8)));
typedef float  floatx4 __attribute__((ext_vector_type(4)));

#define AS1 __attribute__((address_space(1)))
#define AS3 __attribute__((address_space(3)))

// ---------------------------------------------------------------------------
// Prepass: fp32->bf16 (x) and int32->bf16 (wq), one launch.
// Grid-stride, <=2048 blocks (G11), 8 elems/thread: 32B load + 16B store.
// ---------------------------------------------------------------------------
__global__ __launch_bounds__(256)
void cvt_both8(const float* __restrict__ xin, const int* __restrict__ win,
               __bf16* __restrict__ xout, __bf16* __restrict__ wout,
               int nx8, int nw8)
{
    const int stride = gridDim.x * 256;
    const int total  = nx8 + nw8;
    for (int i = blockIdx.x * 256 + threadIdx.x; i < total; i += stride) {
        if (i < nx8) {
            const float4* p = reinterpret_cast<const float4*>(xin) + (size_t)i * 2;
            float4 a = p[0], b = p[1];
            bf16x8 h;
            h[0] = (__bf16)a.x; h[1] = (__bf16)a.y; h[2] = (__bf16)a.z; h[3] = (__bf16)a.w;
            h[4] = (__bf16)b.x; h[5] = (__bf16)b.y; h[6] = (__bf16)b.z; h[7] = (__bf16)b.w;
            reinterpret_cast<bf16x8*>(xout)[i] = h;
        } else {
            int j = i - nx8;
            const int4* p = reinterpret_cast<const int4*>(win) + (size_t)j * 2;
            int4 a = p[0], b = p[1];
            bf16x8 h;
            h[0] = (__bf16)(float)a.x; h[1] = (__bf16)(float)a.y;
            h[2] = (__bf16)(float)a.z; h[3] = (__bf16)(float)a.w;
            h[4] = (__bf16)(float)b.x; h[5] = (__bf16)(float)b.y;
            h[6] = (__bf16)(float)b.z; h[7] = (__bf16)(float)b.w;
            reinterpret_cast<bf16x8*>(wout)[j] = h;
        }
    }
}

// ---------------------------------------------------------------------------
// GEMM v5: 256x256, BK=64, 8 waves (2Mx4N), 4 phases/K-tile.
// Key change vs v4: B-fragment reads for tile kt+1 are ISSUED during P3 of
// tile kt (after the vmcnt(2) publish at end-of-P2) and only WAITED at the
// first MFMA of the next tile -> B ds_reads drain under P3's MFMAs + barrier.
// Each phase now issues only 4 A ds_reads (P3: 4 + 8-for-next, af ordered
// first so fine-grained lgkmcnt releases MFMAs early). kt-loop unrolled x2
// for static bfrA/bfrB ping-pong (rule #20). vmcnt never drained in loop.
//
// FIFO (steady, per tile): P0 issues A(kt+1)q1q3 [2], P1 B(kt+1) [4],
// P2 A(kt+2)q0q2 [2]; wait at end-of-P2 = vmcnt(2) drains through B(kt+1),
// leaving A(kt+2)q0q2 in flight. All A(kt) reads were drained one tile ago.
// ---------------------------------------------------------------------------
#define BM2 256
#define BN2 256
#define BK2 64

template<int P>
__device__ __forceinline__ void phaseAB(const __bf16* cA, const bf16x8 (&bfr)[4][2],
                                        floatx4 (&acc)[8][4],
                                        int wm, int lm, int kq, int sw)
{
    bf16x8 af[2][2];
#pragma unroll
    for (int ii = 0; ii < 2; ++ii)
#pragma unroll
        for (int h = 0; h < 2; ++h)
            af[ii][h] = *reinterpret_cast<const bf16x8*>(
                &cA[(wm + (2 * P + ii) * 16 + lm) * BK2 + ((kq + h * 4) ^ sw) * 8]);
    __builtin_amdgcn_s_setprio(1);
#pragma unroll
    for (int h = 0; h < 2; ++h)
#pragma unroll
        for (int ii = 0; ii < 2; ++ii)
#pragma unroll
            for (int j = 0; j < 4; ++j)
                acc[2 * P + ii][j] = __builtin_amdgcn_mfma_f32_16x16x32_bf16(
                                         af[ii][h], bfr[j][h], acc[2 * P + ii][j], 0, 0, 0);
    __builtin_amdgcn_s_setprio(0);
}

// P3: af reads first (needed now), then next-tile B reads (needed next tile).
__device__ __forceinline__ void phase3(const __bf16* cA, const __bf16* cBn,
                                       const bf16x8 (&bfr)[4][2], bf16x8 (&bfrN)[4][2],
                                       floatx4 (&acc)[8][4],
                                       int wm, int wn, int lm, int kq, int sw)
{
    bf16x8 af[2][2];
#pragma unroll
    for (int ii = 0; ii < 2; ++ii)
#pragma unroll
        for (int h = 0; h < 2; ++h)
            af[ii][h] = *reinterpret_cast<const bf16x8*>(
                &cA[(wm + (6 + ii) * 16 + lm) * BK2 + ((kq + h * 4) ^ sw) * 8]);
#pragma unroll
    for (int j = 0; j < 4; ++j)
#pragma unroll
        for (int h = 0; h < 2; ++h)
            bfrN[j][h] = *reinterpret_cast<const bf16x8*>(
                &cBn[(wn + j * 16 + lm) * BK2 + ((kq + h * 4) ^ sw) * 8]);
    __builtin_amdgcn_s_setprio(1);
#pragma unroll
    for (int h = 0; h < 2; ++h)
#pragma unroll
        for (int ii = 0; ii < 2; ++ii)
#pragma unroll
            for (int j = 0; j < 4; ++j)
                acc[6 + ii][j] = __builtin_amdgcn_mfma_f32_16x16x32_bf16(
                                     af[ii][h], bfr[j][h], acc[6 + ii][j], 0, 0, 0);
    __builtin_amdgcn_s_setprio(0);
}

#define BARRIER() asm volatile("s_barrier" ::: "memory")

__global__ __launch_bounds__(512)
void gemm_bf16_bt_pipe(const __bf16* __restrict__ A, const __bf16* __restrict__ B,
                       const float* __restrict__ scale, const float* __restrict__ bias,
                       float* __restrict__ Out, int M, int N, int K)
{
    __shared__ __bf16 sA[2][BM2 * BK2];   // 64 KB
    __shared__ __bf16 sB[2][BN2 * BK2];   // 64 KB

    const int tid  = threadIdx.x;
    const int wave = tid >> 6;
    const int lane = tid & 63;
    const int row0 = blockIdx.y * BM2;
    const int col0 = blockIdx.x * BN2;

    // staging: one call = 512thr x 16B = 8KB = one 64-row quarter.
    // LDS[row][blk] = G[row][blk ^ (row&7)]  (linear dest, pre-swizzled src).
    const int sRow = lane >> 3;
    const int gBlk = (lane & 7) ^ sRow;
    const size_t aBase = (size_t)(row0 + wave * 8 + sRow) * K + gBlk * 8;
    const size_t bBase = (size_t)(col0 + wave * 8 + sRow) * K + gBlk * 8;
    const int ldsWOff = wave * 8 * BK2;

#define STAGE_A(buf, q, kt_) \
    __builtin_amdgcn_global_load_lds( \
        (const AS1 void*)(A + aBase + (size_t)(q) * 64 * K + (size_t)(kt_) * BK2), \
        (AS3 void*)&sA[(buf)][(q) * 64 * BK2 + ldsWOff], 16, 0, 0)
#define STAGE_B(buf, q, kt_) \
    __builtin_amdgcn_global_load_lds( \
        (const AS1 void*)(B + bBase + (size_t)(q) * 64 * K + (size_t)(kt_) * BK2), \
        (AS3 void*)&sB[(buf)][(q) * 64 * BK2 + ldsWOff], 16, 0, 0)

    // fragment geometry
    const int wm = (wave >> 2) * 128;
    const int wn = (wave & 3) * 64;
    const int lm = lane & 15;
    const int kq = lane >> 4;
    const int sw = lm & 7;

    floatx4 acc[8][4];
#pragma unroll
    for (int i = 0; i < 8; ++i)
#pragma unroll
        for (int j = 0; j < 4; ++j)
            acc[i][j] = (floatx4)0.0f;

    bf16x8 bfrA[4][2], bfrB[4][2];
    const int nt = K / BK2;   // launcher guarantees even, >= 4

    // --- prologue: tile0 full + A(1)q0,q2 (emulates P2 of tile -1)
    STAGE_A(0, 0, 0); STAGE_A(0, 1, 0); STAGE_A(0, 2, 0); STAGE_A(0, 3, 0);
    STAGE_B(0, 0, 0); STAGE_B(0, 1, 0); STAGE_B(0, 2, 0); STAGE_B(0, 3, 0);
    STAGE_A(1, 0, 1); STAGE_A(1, 2, 1);
    asm volatile("s_waitcnt vmcnt(2)" ::: "memory");   // drain through B(0)
    BARRIER();
#pragma unroll
    for (int j = 0; j < 4; ++j)
#pragma unroll
        for (int h = 0; h < 2; ++h)
            bfrA[j][h] = *reinterpret_cast<const bf16x8*>(
                &sB[0][(wn + j * 16 + lm) * BK2 + ((kq + h * 4) ^ sw) * 8]);

    for (int it = 0; it < nt / 2; ++it) {
        const int kt = 2 * it;
        const int n1 = kt + 1;                        // always real
        const int n2 = (kt + 2 < nt) ? kt + 2 : 0;    // phantom keeps FIFO uniform
        const int n3 = (kt + 3 < nt) ? kt + 3 : 0;

        // ================= even tile kt (buf0, B in bfrA) =================
        // P0
        STAGE_A(1, 1, n1); STAGE_A(1, 3, n1);
        phaseAB<0>(sA[0], bfrA, acc, wm, lm, kq, sw);
        BARRIER();
        // P1
        STAGE_B(1, 0, n1); STAGE_B(1, 1, n1); STAGE_B(1, 2, n1); STAGE_B(1, 3, n1);
        phaseAB<1>(sA[0], bfrA, acc, wm, lm, kq, sw);
        BARRIER();
        // P2  (publish: B(kt+1) + all A(kt+1) landed after this barrier)
        STAGE_A(0, 0, n2); STAGE_A(0, 2, n2);
        phaseAB<2>(sA[0], bfrA, acc, wm, lm, kq, sw);
        asm volatile("s_waitcnt vmcnt(2)" ::: "memory");
        BARRIER();
        // P3: compute with bfrA, prefetch next B into bfrB
        phase3(sA[0], sB[1], bfrA, bfrB, acc, wm, wn, lm, kq, sw);
        BARRIER();

        // ================= odd tile kt+1 (buf1, B in bfrB) ================
        // P0
        STAGE_A(0, 1, n2); STAGE_A(0, 3, n2);
        phaseAB<0>(sA[1], bfrB, acc, wm, lm, kq, sw);
        BARRIER();
        // P1
        STAGE_B(0, 0, n2); STAGE_B(0, 1, n2); STAGE_B(0, 2, n2); STAGE_B(0, 3, n2);
        phaseAB<1>(sA[1], bfrB, acc, wm, lm, kq, sw);
        BARRIER();
        // P2
        STAGE_A(1, 0, n3); STAGE_A(1, 2, n3);
        phaseAB<2>(sA[1], bfrB, acc, wm, lm, kq, sw);
        asm volatile("s_waitcnt vmcnt(2)" ::: "memory");
        BARRIER();
        // P3
        phase3(sA[1], sB[0], bfrB, bfrA, acc, wm, wn, lm, kq, sw);
        BARRIER();
    }
    asm volatile("s_waitcnt vmcnt(0)" ::: "memory");  // drain phantoms

    // --- epilogue: C/D layout col=lane&15, row=(lane>>4)*4+reg (m89-verified)
#pragma unroll
    for (int j = 0; j < 4; ++j) {
        int n = col0 + wn + j * 16 + lm;
        float sc = scale[n];
        float bi = bias[n];
#pragma unroll
        for (int i = 0; i < 8; ++i) {
#pragma unroll
            for (int r = 0; r < 4; ++r) {
                int m = row0 + wm + i * 16 + kq * 4 + r;
                Out[(size_t)m * N + n] = sc * acc[i][j][r] + bi;
            }
        }
    }
#undef STAGE_A
#undef STAGE_B
}

// ---------------------------------------------------------------------------
// GEMM fallback: 128x128 tile, BK=64, m97 structure.
// ---------------------------------------------------------------------------
#define BM 128
#define BN 128
#define BK 64

__global__ __launch_bounds__(256)
void gemm_bf16_bt(const __bf16* __restrict__ A, const __bf16* __restrict__ B,
                  const float* __restrict__ scale, const float* __restrict__ bias,
                  float* __restrict__ Out, int M, int N, int K)
{
    __shared__ __bf16 sA[BM * BK];
    __shared__ __bf16 sB[BN * BK];

    const int tid  = threadIdx.x;
    const int row0 = blockIdx.y * BM;
    const int col0 = blockIdx.x * BN;
    const int wave = tid >> 6;
    const int lane = tid & 63;

    const int sRow = lane >> 3;
    const int gBlk = (lane & 7) ^ sRow;
    size_t aOff[4], bOff[4];
    const __bf16* ldsA[4];
    const __bf16* ldsB[4];
#pragma unroll
    for (int q = 0; q < 4; ++q) {
        int r = wave * 32 + q * 8 + sRow;
        aOff[q] = (size_t)(row0 + r) * K + gBlk * 8;
        bOff[q] = (size_t)(col0 + r) * K + gBlk * 8;
        ldsA[q] = &sA[(wave * 32 + q * 8) * BK];
        ldsB[q] = &sB[(wave * 32 + q * 8) * BK];
    }

    const int wm = (wave >> 1) * 64;
    const int wn = (wave & 1) * 64;
    const int lm = lane & 15;
    const int kq = lane >> 4;
    const int sw = lm & 7;

    floatx4 acc[4][4];
#pragma unroll
    for (int i = 0; i < 4; ++i)
#pragma unroll
        for (int j = 0; j < 4; ++j)
            acc[i][j] = (floatx4)0.0f;

    for (int k0 = 0; k0 < K; k0 += BK) {
#pragma unroll
        for (int q = 0; q < 4; ++q) {
            __builtin_amdgcn_global_load_lds((const AS1 void*)(A + aOff[q] + k0),
                                             (AS3 void*)ldsA[q], 16, 0, 0);
            __builtin_amdgcn_global_load_lds((const AS1 void*)(B + bOff[q] + k0),
                                             (AS3 void*)ldsB[q], 16, 0, 0);
        }
        __syncthreads();

#pragma unroll
        for (int h = 0; h < 2; ++h) {
            const int blkA = (kq + h * 4);
            bf16x8 af[4], bfr[4];
#pragma unroll
            for (int i = 0; i < 4; ++i) {
                int row = wm + i * 16 + lm;
                af[i] = *reinterpret_cast<const bf16x8*>(
                            &sA[row * BK + (blkA ^ sw) * 8]);
            }
#pragma unroll
            for (int j = 0; j < 4; ++j) {
                int row = wn + j * 16 + lm;
                bfr[j] = *reinterpret_cast<const bf16x8*>(
                            &sB[row * BK + (blkA ^ sw) * 8]);
            }
#pragma unroll
            for (int i = 0; i < 4; ++i)
#pragma unroll
                for (int j = 0; j < 4; ++j)
                    acc[i][j] = __builtin_amdgcn_mfma_f32_16x16x32_bf16(
                                    af[i], bfr[j], acc[i][j], 0, 0, 0);
        }
        __syncthreads();
    }

#pragma unroll
    for (int j = 0; j < 4; ++j) {
        int n = col0 + wn + j * 16 + lm;
        float sc = scale[n];
        float bi = bias[n];
#pragma unroll
        for (int i = 0; i < 4; ++i) {
#pragma unroll
            for (int r = 0; r < 4; ++r) {
                int m = row0 + wm + i * 16 + kq * 4 + r;
                Out[(size_t)m * N + n] = sc * acc[i][j][r] + bi;
            }
        }
    }
}

// ---------------------------------------------------------------------------
// Fallback: fused conversion in staging, no workspace needed.
// ---------------------------------------------------------------------------
__global__ __launch_bounds__(256)
void fp4linear_gemm(const float* __restrict__ X, const int* __restrict__ W,
                    const float* __restrict__ scale, const float* __restrict__ bias,
                    float* __restrict__ Out, int M, int N, int K)
{
    __shared__ __bf16 sA[BM * 32];
    __shared__ __bf16 sB[BN * 32];

    const int tid  = threadIdx.x;
    const int row0 = blockIdx.y * BM;
    const int col0 = blockIdx.x * BN;
    const int wave = tid >> 6;
    const int lane = tid & 63;
    const int wm = (wave >> 1) * 64;
    const int wn = (wave & 1) * 64;
    const int lm = lane & 15;
    const int kq = lane >> 4;

    floatx4 acc[4][4];
#pragma unroll
    for (int i = 0; i < 4; ++i)
#pragma unroll
        for (int j = 0; j < 4; ++j)
            acc[i][j] = (floatx4)0.0f;

    for (int k0 = 0; k0 < K; k0 += 32) {
        float4 fa[4];
        int4   ib[4];
#pragma unroll
        for (int l = 0; l < 4; ++l) {
            int idx = tid + l * 256;
            int r = idx >> 3, c4 = idx & 7;
            fa[l] = *reinterpret_cast<const float4*>(
                        &X[(size_t)(row0 + r) * K + k0 + c4 * 4]);
        }
#pragma unroll
        for (int l = 0; l < 4; ++l) {
            int idx = tid + l * 256;
            int r = idx >> 3, c4 = idx & 7;
            ib[l] = *reinterpret_cast<const int4*>(
                        &W[(size_t)(col0 + r) * K + k0 + c4 * 4]);
        }
        __syncthreads();
#pragma unroll
        for (int l = 0; l < 4; ++l) {
            int idx = tid + l * 256;
            int r = idx >> 3, c4 = idx & 7;
            bf16x4 h;
            h[0] = (__bf16)fa[l].x; h[1] = (__bf16)fa[l].y;
            h[2] = (__bf16)fa[l].z; h[3] = (__bf16)fa[l].w;
            *reinterpret_cast<bf16x4*>(&sA[r * 32 + c4 * 4]) = h;
        }
#pragma unroll
        for (int l = 0; l < 4; ++l) {
            int idx = tid + l * 256;
            int r = idx >> 3, c4 = idx & 7;
            bf16x4 h;
            h[0] = (__bf16)(float)ib[l].x; h[1] = (__bf16)(float)ib[l].y;
            h[2] = (__bf16)(float)ib[l].z; h[3] = (__bf16)(float)ib[l].w;
            *reinterpret_cast<bf16x4*>(&sB[r * 32 + c4 * 4]) = h;
        }
        __syncthreads();

        bf16x8 af[4], bfr[4];
#pragma unroll
        for (int i = 0; i < 4; ++i)
            af[i] = *reinterpret_cast<const bf16x8*>(
                        &sA[(wm + i * 16 + lm) * 32 + kq * 8]);
#pragma unroll
        for (int j = 0; j < 4; ++j)
            bfr[j] = *reinterpret_cast<const bf16x8*>(
                        &sB[(wn + j * 16 + lm) * 32 + kq * 8]);
#pragma unroll
        for (int i = 0; i < 4; ++i)
#pragma unroll
            for (int j = 0; j < 4; ++j)
                acc[i][j] = __builtin_amdgcn_mfma_f32_16x16x32_bf16(
                                af[i], bfr[j], acc[i][j], 0, 0, 0);
    }

#pragma unroll
    for (int j = 0; j < 4; ++j) {
        int n = col0 + wn + j * 16 + lm;
        float sc = scale[n];
        float bi = bias[n];
#pragma unroll
        for (int i = 0; i < 4; ++i) {
#pragma unroll
            for (int r = 0; r < 4; ++r) {
                int m = row0 + wm + i * 16 + kq * 4 + r;
                Out[(size_t)m * N + n] = sc * acc[i][j][r] + bi;
            }
        }
    }
}

extern "C" void kernel_launch(void* const* d_in, const int* in_sizes, int n_in,
                              void* d_out, int out_size, void* d_ws, size_t ws_size,
                              hipStream_t stream) {
    const float* x     = (const float*)d_in[0];
    const int*   wq    = (const int*)d_in[1];
    const float* scale = (const float*)d_in[2];
    const float* bias  = (const float*)d_in[3];
    float* out = (float*)d_out;

    const int N = in_sizes[2];            // OUT = 4096
    const int K = in_sizes[1] / N;        // IN  = 4096
    const int M = in_sizes[0] / K;        // B*S = 8192

    const size_t xElems = (size_t)M * K;
    const size_t wElems = (size_t)N * K;
    const size_t need   = (xElems + wElems) * sizeof(__bf16);

    const bool cvt_ok = (ws_size >= need) && (xElems % 8 == 0) && (wElems % 8 == 0);
    const int  nt     = K / BK2;

    if (cvt_ok) {
        __bf16* xb = (__bf16*)d_ws;
        __bf16* wb = xb + xElems;
        int nx8 = (int)(xElems / 8);
        int nw8 = (int)(wElems / 8);
        int total = nx8 + nw8;
        int cvtBlocks = (total + 255) / 256;
        if (cvtBlocks > 2048) cvtBlocks = 2048;
        hipLaunchKernelGGL(cvt_both8, dim3(cvtBlocks), dim3(256), 0, stream,
                           x, wq, xb, wb, nx8, nw8);
        if ((M % BM2 == 0) && (N % BN2 == 0) && (K % BK2 == 0) &&
            (nt % 2 == 0) && (nt >= 4)) {
            hipLaunchKernelGGL(gemm_bf16_bt_pipe, dim3(N / BN2, M / BM2), dim3(512),
                               0, stream, xb, wb, scale, bias, out, M, N, K);
        } else if ((M % BM == 0) && (N % BN == 0) && (K % BK == 0)) {
            hipLaunchKernelGGL(gemm_bf16_bt, dim3(N / BN, M / BM), dim3(256),
                               0, stream, xb, wb, scale, bias, out, M, N, K);
        } else {
            hipLaunchKernelGGL(fp4linear_gemm, dim3(N / BN, M / BM), dim3(256),
                               0, stream, x, wq, scale, bias, out, M, N, K);
        }
    } else {
        hipLaunchKernelGGL(fp4linear_gemm, dim3(N / BN, M / BM), dim3(256), 0, stream,
                           x, wq, scale, bias, out, M, N, K);
    }
}

// Round 3
// 532.180 us; speedup vs baseline: 1.1174x; 1.0247x over previous
//
#include <hip/hip_runtime.h>
#include <hip/hip_bf16.h>

typedef __bf16 bf16x4 __attribute__((ext_vector_type(4)));
typedef __bf16 bf16x8 __attribute__((ext_vector_type(8)));
typedef float  floatx4 __attribute__((ext_vector_type(4)));

#define AS1 __attribute__((address_space(1)))
#define AS3 __attribute__((address_space(3)))

// ---------------------------------------------------------------------------
// Prepass: fp32->bf16 (x) and int32->bf16 (wq), one launch.
// Grid-stride, <=2048 blocks (G11), 8 elems/thread: 32B load + 16B store.
// ---------------------------------------------------------------------------
__global__ __launch_bounds__(256)
void cvt_both8(const float* __restrict__ xin, const int* __restrict__ win,
               __bf16* __restrict__ xout, __bf16* __restrict__ wout,
               int nx8, int nw8)
{
    const int stride = gridDim.x * 256;
    const int total  = nx8 + nw8;
    for (int i = blockIdx.x * 256 + threadIdx.x; i < total; i += stride) {
        if (i < nx8) {
            const float4* p = reinterpret_cast<const float4*>(xin) + (size_t)i * 2;
            float4 a = p[0], b = p[1];
            bf16x8 h;
            h[0] = (__bf16)a.x; h[1] = (__bf16)a.y; h[2] = (__bf16)a.z; h[3] = (__bf16)a.w;
            h[4] = (__bf16)b.x; h[5] = (__bf16)b.y; h[6] = (__bf16)b.z; h[7] = (__bf16)b.w;
            reinterpret_cast<bf16x8*>(xout)[i] = h;
        } else {
            int j = i - nx8;
            const int4* p = reinterpret_cast<const int4*>(win) + (size_t)j * 2;
            int4 a = p[0], b = p[1];
            bf16x8 h;
            h[0] = (__bf16)(float)a.x; h[1] = (__bf16)(float)a.y;
            h[2] = (__bf16)(float)a.z; h[3] = (__bf16)(float)a.w;
            h[4] = (__bf16)(float)b.x; h[5] = (__bf16)(float)b.y;
            h[6] = (__bf16)(float)b.z; h[7] = (__bf16)(float)b.w;
            reinterpret_cast<bf16x8*>(wout)[j] = h;
        }
    }
}

// ---------------------------------------------------------------------------
// GEMM v6: 256x256, BK=64, 8 waves (2Mx4N), 4 phases/K-tile.
// Change vs v5: DEEP B staging. B lives in registers for its consumption
// tile (bfr read at P3 of kt-1), so LDS sB[c^1] is dead one tile earlier
// than v5 used. Tile kt now stages B(kt+2) -> sB[c]; B(kt+1) was staged at
// P1 of tile kt-1 -> ~5 phases (~3800 cyc) of cover before its P3 read
// (v5 gave it ~1 phase, the diagnosed whole-CU vm-stall). Single per-tile
// wait: vmcnt(8) at end-of-P2 (drains through A(kt+1)q0q2 from P2 of kt-1;
// leaves exactly this tile's 8 issues). vmcnt never drained in the loop.
//
// Per-tile issue FIFO: P0: A(kt+1)q1,q3 [2] -> sA[c^1]
//                      P1: B(kt+2) x4   [4] -> sB[c]
//                      P2: A(kt+2)q0,q2 [2] -> sA[c]
// Cover: B(kt+1): 5 phases; A q0q2: 4 phases; A q1q3: 6 phases.
// Liveness: sB[c] old content B(kt) consumed into regs by P0's MFMAs
// (P0-end barrier precedes the P1 write); sA overwrites follow v5's
// quadrant-by-m argument. Phantom clamps keep FIFO uniform at the tail.
// ---------------------------------------------------------------------------
#define BM2 256
#define BN2 256
#define BK2 64

template<int P>
__device__ __forceinline__ void phaseAB(const __bf16* cA, const bf16x8 (&bfr)[4][2],
                                        floatx4 (&acc)[8][4],
                                        int wm, int lm, int kq, int sw)
{
    bf16x8 af[2][2];
#pragma unroll
    for (int ii = 0; ii < 2; ++ii)
#pragma unroll
        for (int h = 0; h < 2; ++h)
            af[ii][h] = *reinterpret_cast<const bf16x8*>(
                &cA[(wm + (2 * P + ii) * 16 + lm) * BK2 + ((kq + h * 4) ^ sw) * 8]);
    __builtin_amdgcn_s_setprio(1);
#pragma unroll
    for (int h = 0; h < 2; ++h)
#pragma unroll
        for (int ii = 0; ii < 2; ++ii)
#pragma unroll
            for (int j = 0; j < 4; ++j)
                acc[2 * P + ii][j] = __builtin_amdgcn_mfma_f32_16x16x32_bf16(
                                         af[ii][h], bfr[j][h], acc[2 * P + ii][j], 0, 0, 0);
    __builtin_amdgcn_s_setprio(0);
}

// P3: af reads first (needed now), then next-tile B reads (needed next tile).
__device__ __forceinline__ void phase3(const __bf16* cA, const __bf16* cBn,
                                       const bf16x8 (&bfr)[4][2], bf16x8 (&bfrN)[4][2],
                                       floatx4 (&acc)[8][4],
                                       int wm, int wn, int lm, int kq, int sw)
{
    bf16x8 af[2][2];
#pragma unroll
    for (int ii = 0; ii < 2; ++ii)
#pragma unroll
        for (int h = 0; h < 2; ++h)
            af[ii][h] = *reinterpret_cast<const bf16x8*>(
                &cA[(wm + (6 + ii) * 16 + lm) * BK2 + ((kq + h * 4) ^ sw) * 8]);
#pragma unroll
    for (int j = 0; j < 4; ++j)
#pragma unroll
        for (int h = 0; h < 2; ++h)
            bfrN[j][h] = *reinterpret_cast<const bf16x8*>(
                &cBn[(wn + j * 16 + lm) * BK2 + ((kq + h * 4) ^ sw) * 8]);
    __builtin_amdgcn_s_setprio(1);
#pragma unroll
    for (int h = 0; h < 2; ++h)
#pragma unroll
        for (int ii = 0; ii < 2; ++ii)
#pragma unroll
            for (int j = 0; j < 4; ++j)
                acc[6 + ii][j] = __builtin_amdgcn_mfma_f32_16x16x32_bf16(
                                     af[ii][h], bfr[j][h], acc[6 + ii][j], 0, 0, 0);
    __builtin_amdgcn_s_setprio(0);
}

#define BARRIER() asm volatile("s_barrier" ::: "memory")

__global__ __launch_bounds__(512)
void gemm_bf16_bt_pipe(const __bf16* __restrict__ A, const __bf16* __restrict__ B,
                       const float* __restrict__ scale, const float* __restrict__ bias,
                       float* __restrict__ Out, int M, int N, int K)
{
    __shared__ __bf16 sA[2][BM2 * BK2];   // 64 KB
    __shared__ __bf16 sB[2][BN2 * BK2];   // 64 KB

    const int tid  = threadIdx.x;
    const int wave = tid >> 6;
    const int lane = tid & 63;
    const int row0 = blockIdx.y * BM2;
    const int col0 = blockIdx.x * BN2;

    // staging: one call = 512thr x 16B = 8KB = one 64-row quarter.
    // LDS[row][blk] = G[row][blk ^ (row&7)]  (linear dest, pre-swizzled src).
    const int sRow = lane >> 3;
    const int gBlk = (lane & 7) ^ sRow;
    const size_t aBase = (size_t)(row0 + wave * 8 + sRow) * K + gBlk * 8;
    const size_t bBase = (size_t)(col0 + wave * 8 + sRow) * K + gBlk * 8;
    const int ldsWOff = wave * 8 * BK2;

#define STAGE_A(buf, q, kt_) \
    __builtin_amdgcn_global_load_lds( \
        (const AS1 void*)(A + aBase + (size_t)(q) * 64 * K + (size_t)(kt_) * BK2), \
        (AS3 void*)&sA[(buf)][(q) * 64 * BK2 + ldsWOff], 16, 0, 0)
#define STAGE_B(buf, q, kt_) \
    __builtin_amdgcn_global_load_lds( \
        (const AS1 void*)(B + bBase + (size_t)(q) * 64 * K + (size_t)(kt_) * BK2), \
        (AS3 void*)&sB[(buf)][(q) * 64 * BK2 + ldsWOff], 16, 0, 0)

    // fragment geometry
    const int wm = (wave >> 2) * 128;
    const int wn = (wave & 3) * 64;
    const int lm = lane & 15;
    const int kq = lane >> 4;
    const int sw = lm & 7;

    floatx4 acc[8][4];
#pragma unroll
    for (int i = 0; i < 8; ++i)
#pragma unroll
        for (int j = 0; j < 4; ++j)
            acc[i][j] = (floatx4)0.0f;

    bf16x8 bfrA[4][2], bfrB[4][2];
    const int nt = K / BK2;   // launcher guarantees even, >= 4

    // --- prologue (emulates tiles -2/-1 of the steady FIFO):
    //   A(0) full + B(0) full -> bufs 0
    //   B(1) x4 -> sB[1]   (emulates P1 of tile -1)
    //   A(1) q0,q2 -> sA[1] (emulates P2 of tile -1)
    STAGE_A(0, 0, 0); STAGE_A(0, 1, 0); STAGE_A(0, 2, 0); STAGE_A(0, 3, 0);
    STAGE_B(0, 0, 0); STAGE_B(0, 1, 0); STAGE_B(0, 2, 0); STAGE_B(0, 3, 0);
    STAGE_B(1, 0, 1); STAGE_B(1, 1, 1); STAGE_B(1, 2, 1); STAGE_B(1, 3, 1);
    STAGE_A(1, 0, 1); STAGE_A(1, 2, 1);
    asm volatile("s_waitcnt vmcnt(6)" ::: "memory");   // drain A(0)+B(0)
    BARRIER();
#pragma unroll
    for (int j = 0; j < 4; ++j)
#pragma unroll
        for (int h = 0; h < 2; ++h)
            bfrA[j][h] = *reinterpret_cast<const bf16x8*>(
                &sB[0][(wn + j * 16 + lm) * BK2 + ((kq + h * 4) ^ sw) * 8]);

    for (int it = 0; it < nt / 2; ++it) {
        const int kt = 2 * it;
        const int n1 = kt + 1;                        // always real
        const int n2 = (kt + 2 < nt) ? kt + 2 : 0;    // phantom keeps FIFO uniform
        const int n3 = (kt + 3 < nt) ? kt + 3 : 0;

        // ================= even tile kt (buf0, B in bfrA) =================
        // P0
        STAGE_A(1, 1, n1); STAGE_A(1, 3, n1);
        phaseAB<0>(sA[0], bfrA, acc, wm, lm, kq, sw);
        BARRIER();
        // P1: deep-B — stage B(kt+2) into sB[0] (B(kt) already in registers)
        STAGE_B(0, 0, n2); STAGE_B(0, 1, n2); STAGE_B(0, 2, n2); STAGE_B(0, 3, n2);
        phaseAB<1>(sA[0], bfrA, acc, wm, lm, kq, sw);
        BARRIER();
        // P2  (publish: drains through A(kt+1)q0q2; leaves this tile's 8)
        STAGE_A(0, 0, n2); STAGE_A(0, 2, n2);
        phaseAB<2>(sA[0], bfrA, acc, wm, lm, kq, sw);
        asm volatile("s_waitcnt vmcnt(8)" ::: "memory");
        BARRIER();
        // P3: compute with bfrA, prefetch B(kt+1) (staged last tile) into bfrB
        phase3(sA[0], sB[1], bfrA, bfrB, acc, wm, wn, lm, kq, sw);
        BARRIER();

        // ================= odd tile kt+1 (buf1, B in bfrB) ================
        // P0
        STAGE_A(0, 1, n2); STAGE_A(0, 3, n2);
        phaseAB<0>(sA[1], bfrB, acc, wm, lm, kq, sw);
        BARRIER();
        // P1: stage B(kt+3) into sB[1]
        STAGE_B(1, 0, n3); STAGE_B(1, 1, n3); STAGE_B(1, 2, n3); STAGE_B(1, 3, n3);
        phaseAB<1>(sA[1], bfrB, acc, wm, lm, kq, sw);
        BARRIER();
        // P2
        STAGE_A(1, 0, n3); STAGE_A(1, 2, n3);
        phaseAB<2>(sA[1], bfrB, acc, wm, lm, kq, sw);
        asm volatile("s_waitcnt vmcnt(8)" ::: "memory");
        BARRIER();
        // P3
        phase3(sA[1], sB[0], bfrB, bfrA, acc, wm, wn, lm, kq, sw);
        BARRIER();
    }
    asm volatile("s_waitcnt vmcnt(0)" ::: "memory");  // drain phantoms before exit

    // --- epilogue: C/D layout col=lane&15, row=(lane>>4)*4+reg (m89-verified)
#pragma unroll
    for (int j = 0; j < 4; ++j) {
        int n = col0 + wn + j * 16 + lm;
        float sc = scale[n];
        float bi = bias[n];
#pragma unroll
        for (int i = 0; i < 8; ++i) {
#pragma unroll
            for (int r = 0; r < 4; ++r) {
                int m = row0 + wm + i * 16 + kq * 4 + r;
                Out[(size_t)m * N + n] = sc * acc[i][j][r] + bi;
            }
        }
    }
#undef STAGE_A
#undef STAGE_B
}

// ---------------------------------------------------------------------------
// GEMM fallback: 128x128 tile, BK=64, m97 structure.
// ---------------------------------------------------------------------------
#define BM 128
#define BN 128
#define BK 64

__global__ __launch_bounds__(256)
void gemm_bf16_bt(const __bf16* __restrict__ A, const __bf16* __restrict__ B,
                  const float* __restrict__ scale, const float* __restrict__ bias,
                  float* __restrict__ Out, int M, int N, int K)
{
    __shared__ __bf16 sA[BM * BK];
    __shared__ __bf16 sB[BN * BK];

    const int tid  = threadIdx.x;
    const int row0 = blockIdx.y * BM;
    const int col0 = blockIdx.x * BN;
    const int wave = tid >> 6;
    const int lane = tid & 63;

    const int sRow = lane >> 3;
    const int gBlk = (lane & 7) ^ sRow;
    size_t aOff[4], bOff[4];
    const __bf16* ldsA[4];
    const __bf16* ldsB[4];
#pragma unroll
    for (int q = 0; q < 4; ++q) {
        int r = wave * 32 + q * 8 + sRow;
        aOff[q] = (size_t)(row0 + r) * K + gBlk * 8;
        bOff[q] = (size_t)(col0 + r) * K + gBlk * 8;
        ldsA[q] = &sA[(wave * 32 + q * 8) * BK];
        ldsB[q] = &sB[(wave * 32 + q * 8) * BK];
    }

    const int wm = (wave >> 1) * 64;
    const int wn = (wave & 1) * 64;
    const int lm = lane & 15;
    const int kq = lane >> 4;
    const int sw = lm & 7;

    floatx4 acc[4][4];
#pragma unroll
    for (int i = 0; i < 4; ++i)
#pragma unroll
        for (int j = 0; j < 4; ++j)
            acc[i][j] = (floatx4)0.0f;

    for (int k0 = 0; k0 < K; k0 += BK) {
#pragma unroll
        for (int q = 0; q < 4; ++q) {
            __builtin_amdgcn_global_load_lds((const AS1 void*)(A + aOff[q] + k0),
                                             (AS3 void*)ldsA[q], 16, 0, 0);
            __builtin_amdgcn_global_load_lds((const AS1 void*)(B + bOff[q] + k0),
                                             (AS3 void*)ldsB[q], 16, 0, 0);
        }
        __syncthreads();

#pragma unroll
        for (int h = 0; h < 2; ++h) {
            const int blkA = (kq + h * 4);
            bf16x8 af[4], bfr[4];
#pragma unroll
            for (int i = 0; i < 4; ++i) {
                int row = wm + i * 16 + lm;
                af[i] = *reinterpret_cast<const bf16x8*>(
                            &sA[row * BK + (blkA ^ sw) * 8]);
            }
#pragma unroll
            for (int j = 0; j < 4; ++j) {
                int row = wn + j * 16 + lm;
                bfr[j] = *reinterpret_cast<const bf16x8*>(
                            &sB[row * BK + (blkA ^ sw) * 8]);
            }
#pragma unroll
            for (int i = 0; i < 4; ++i)
#pragma unroll
                for (int j = 0; j < 4; ++j)
                    acc[i][j] = __builtin_amdgcn_mfma_f32_16x16x32_bf16(
                                    af[i], bfr[j], acc[i][j], 0, 0, 0);
        }
        __syncthreads();
    }

#pragma unroll
    for (int j = 0; j < 4; ++j) {
        int n = col0 + wn + j * 16 + lm;
        float sc = scale[n];
        float bi = bias[n];
#pragma unroll
        for (int i = 0; i < 4; ++i) {
#pragma unroll
            for (int r = 0; r < 4; ++r) {
                int m = row0 + wm + i * 16 + kq * 4 + r;
                Out[(size_t)m * N + n] = sc * acc[i][j][r] + bi;
            }
        }
    }
}

// ---------------------------------------------------------------------------
// Fallback: fused conversion in staging, no workspace needed.
// ---------------------------------------------------------------------------
__global__ __launch_bounds__(256)
void fp4linear_gemm(const float* __restrict__ X, const int* __restrict__ W,
                    const float* __restrict__ scale, const float* __restrict__ bias,
                    float* __restrict__ Out, int M, int N, int K)
{
    __shared__ __bf16 sA[BM * 32];
    __shared__ __bf16 sB[BN * 32];

    const int tid  = threadIdx.x;
    const int row0 = blockIdx.y * BM;
    const int col0 = blockIdx.x * BN;
    const int wave = tid >> 6;
    const int lane = tid & 63;
    const int wm = (wave >> 1) * 64;
    const int wn = (wave & 1) * 64;
    const int lm = lane & 15;
    const int kq = lane >> 4;

    floatx4 acc[4][4];
#pragma unroll
    for (int i = 0; i < 4; ++i)
#pragma unroll
        for (int j = 0; j < 4; ++j)
            acc[i][j] = (floatx4)0.0f;

    for (int k0 = 0; k0 < K; k0 += 32) {
        float4 fa[4];
        int4   ib[4];
#pragma unroll
        for (int l = 0; l < 4; ++l) {
            int idx = tid + l * 256;
            int r = idx >> 3, c4 = idx & 7;
            fa[l] = *reinterpret_cast<const float4*>(
                        &X[(size_t)(row0 + r) * K + k0 + c4 * 4]);
        }
#pragma unroll
        for (int l = 0; l < 4; ++l) {
            int idx = tid + l * 256;
            int r = idx >> 3, c4 = idx & 7;
            ib[l] = *reinterpret_cast<const int4*>(
                        &W[(size_t)(col0 + r) * K + k0 + c4 * 4]);
        }
        __syncthreads();
#pragma unroll
        for (int l = 0; l < 4; ++l) {
            int idx = tid + l * 256;
            int r = idx >> 3, c4 = idx & 7;
            bf16x4 h;
            h[0] = (__bf16)fa[l].x; h[1] = (__bf16)fa[l].y;
            h[2] = (__bf16)fa[l].z; h[3] = (__bf16)fa[l].w;
            *reinterpret_cast<bf16x4*>(&sA[r * 32 + c4 * 4]) = h;
        }
#pragma unroll
        for (int l = 0; l < 4; ++l) {
            int idx = tid + l * 256;
            int r = idx >> 3, c4 = idx & 7;
            bf16x4 h;
            h[0] = (__bf16)(float)ib[l].x; h[1] = (__bf16)(float)ib[l].y;
            h[2] = (__bf16)(float)ib[l].z; h[3] = (__bf16)(float)ib[l].w;
            *reinterpret_cast<bf16x4*>(&sB[r * 32 + c4 * 4]) = h;
        }
        __syncthreads();

        bf16x8 af[4], bfr[4];
#pragma unroll
        for (int i = 0; i < 4; ++i)
            af[i] = *reinterpret_cast<const bf16x8*>(
                        &sA[(wm + i * 16 + lm) * 32 + kq * 8]);
#pragma unroll
        for (int j = 0; j < 4; ++j)
            bfr[j] = *reinterpret_cast<const bf16x8*>(
                        &sB[(wn + j * 16 + lm) * 32 + kq * 8]);
#pragma unroll
        for (int i = 0; i < 4; ++i)
#pragma unroll
            for (int j = 0; j < 4; ++j)
                acc[i][j] = __builtin_amdgcn_mfma_f32_16x16x32_bf16(
                                af[i], bfr[j], acc[i][j], 0, 0, 0);
    }

#pragma unroll
    for (int j = 0; j < 4; ++j) {
        int n = col0 + wn + j * 16 + lm;
        float sc = scale[n];
        float bi = bias[n];
#pragma unroll
        for (int i = 0; i < 4; ++i) {
#pragma unroll
            for (int r = 0; r < 4; ++r) {
                int m = row0 + wm + i * 16 + kq * 4 + r;
                Out[(size_t)m * N + n] = sc * acc[i][j][r] + bi;
            }
        }
    }
}

extern "C" void kernel_launch(void* const* d_in, const int* in_sizes, int n_in,
                              void* d_out, int out_size, void* d_ws, size_t ws_size,
                              hipStream_t stream) {
    const float* x     = (const float*)d_in[0];
    const int*   wq    = (const int*)d_in[1];
    const float* scale = (const float*)d_in[2];
    const float* bias  = (const float*)d_in[3];
    float* out = (float*)d_out;

    const int N = in_sizes[2];            // OUT = 4096
    const int K = in_sizes[1] / N;        // IN  = 4096
    const int M = in_sizes[0] / K;        // B*S = 8192

    const size_t xElems = (size_t)M * K;
    const size_t wElems = (size_t)N * K;
    const size_t need   = (xElems + wElems) * sizeof(__bf16);

    const bool cvt_ok = (ws_size >= need) && (xElems % 8 == 0) && (wElems % 8 == 0);
    const int  nt     = K / BK2;

    if (cvt_ok) {
        __bf16* xb = (__bf16*)d_ws;
        __bf16* wb = xb + xElems;
        int nx8 = (int)(xElems / 8);
        int nw8 = (int)(wElems / 8);
        int total = nx8 + nw8;
        int cvtBlocks = (total + 255) / 256;
        if (cvtBlocks > 2048) cvtBlocks = 2048;
        hipLaunchKernelGGL(cvt_both8, dim3(cvtBlocks), dim3(256), 0, stream,
                           x, wq, xb, wb, nx8, nw8);
        if ((M % BM2 == 0) && (N % BN2 == 0) && (K % BK2 == 0) &&
            (nt % 2 == 0) && (nt >= 4)) {
            hipLaunchKernelGGL(gemm_bf16_bt_pipe, dim3(N / BN2, M / BM2), dim3(512),
                               0, stream, xb, wb, scale, bias, out, M, N, K);
        } else if ((M % BM == 0) && (N % BN == 0) && (K % BK == 0)) {
            hipLaunchKernelGGL(gemm_bf16_bt, dim3(N / BN, M / BM), dim3(256),
                               0, stream, xb, wb, scale, bias, out, M, N, K);
        } else {
            hipLaunchKernelGGL(fp4linear_gemm, dim3(N / BN, M / BM), dim3(256),
                               0, stream, x, wq, scale, bias, out, M, N, K);
        }
    } else {
        hipLaunchKernelGGL(fp4linear_gemm, dim3(N / BN, M / BM), dim3(256), 0, stream,
                           x, wq, scale, bias, out, M, N, K);
    }
}

// Round 4
// 506.974 us; speedup vs baseline: 1.1730x; 1.0497x over previous
//
#include <hip/hip_runtime.h>
#include <hip/hip_bf16.h>

typedef __bf16 bf16x4 __attribute__((ext_vector_type(4)));
typedef __bf16 bf16x8 __attribute__((ext_vector_type(8)));
typedef float  floatx4 __attribute__((ext_vector_type(4)));

#define AS1 __attribute__((address_space(1)))
#define AS3 __attribute__((address_space(3)))

// ---------------------------------------------------------------------------
// Prepass: fp32->bf16 (x) and int32->bf16 (wq), one launch.
// Grid-stride, <=2048 blocks (G11), 8 elems/thread.
// ---------------------------------------------------------------------------
__global__ __launch_bounds__(256)
void cvt_both8(const float* __restrict__ xin, const int* __restrict__ win,
               __bf16* __restrict__ xout, __bf16* __restrict__ wout,
               int nx8, int nw8)
{
    const int stride = gridDim.x * 256;
    const int total  = nx8 + nw8;
    for (int i = blockIdx.x * 256 + threadIdx.x; i < total; i += stride) {
        if (i < nx8) {
            const float4* p = reinterpret_cast<const float4*>(xin) + (size_t)i * 2;
            float4 a = p[0], b = p[1];
            bf16x8 h;
            h[0] = (__bf16)a.x; h[1] = (__bf16)a.y; h[2] = (__bf16)a.z; h[3] = (__bf16)a.w;
            h[4] = (__bf16)b.x; h[5] = (__bf16)b.y; h[6] = (__bf16)b.z; h[7] = (__bf16)b.w;
            reinterpret_cast<bf16x8*>(xout)[i] = h;
        } else {
            int j = i - nx8;
            const int4* p = reinterpret_cast<const int4*>(win) + (size_t)j * 2;
            int4 a = p[0], b = p[1];
            bf16x8 h;
            h[0] = (__bf16)(float)a.x; h[1] = (__bf16)(float)a.y;
            h[2] = (__bf16)(float)a.z; h[3] = (__bf16)(float)a.w;
            h[4] = (__bf16)(float)b.x; h[5] = (__bf16)(float)b.y;
            h[6] = (__bf16)(float)b.z; h[7] = (__bf16)(float)b.w;
            reinterpret_cast<bf16x8*>(wout)[j] = h;
        }
    }
}

// ---------------------------------------------------------------------------
// GEMM v7: 256x256, BK=64, 8 waves (2Mx4N), 4 phases/K-tile.
// All operand ds_reads pipelined ONE PHASE AHEAD (m201 pattern): each
// phase's af/bf fragments were read before the barrier that precedes the
// phase, so read latency drains under barrier skew + prior MFMAs, and each
// freshly-staged LDS region is consumed only after {per-wave vmcnt +
// barrier} (vmcnt covers only the issuing wave's loads — v6's race fixed).
//
// Per-tile issue/consume schedule (tile kt, buf c=kt&1, reads at phase END):
//   P0: stage A(kt+1)q1q3->sA[c^1]; MFMA rows01(afE); read afO<-cA rows+32;
//       vmcnt(8)  [drains A(kt)q1q3];  BARRIER
//   P1: stage B(kt+2)x4 -> sB[c];    MFMA rows23(afO); read afE<-cA rows+64; BARRIER
//   P2: stage A(kt+2)q0q2->sA[c];    MFMA rows45(afE); read afO<-cA rows+96;
//       vmcnt(8)  [drains B(kt+1), A(kt+1)q0q2];  BARRIER
//   P3: MFMA rows67(afO); read bfr<-sB[c^1] (B(kt+1)); read afE<-sA[c^1] rows+0; BARRIER
// Steady outstanding at tile entry: [A(kt)q1q3(2)][B(kt+1)(4)][A(kt+1)q0q2(2)]=8.
// Cover: every load >=4 phases before its consuming read. vmcnt never 0.
// Liveness: q0/q2 of sA[c] last read P0-end, overwritten P2 (barrier between);
// q1/q3 last read P2-end, overwritten next-tile P0; sB[c] last read kt-1 P3,
// overwritten kt P1; all with >=1 barrier separation.
// ---------------------------------------------------------------------------
#define BM2 256
#define BN2 256
#define BK2 64

#define BARRIER() asm volatile("s_barrier" ::: "memory")

template<int P>
__device__ __forceinline__ void mfma_cluster(floatx4 (&acc)[8][4],
                                             const bf16x8 (&af)[2][2],
                                             const bf16x8 (&bfr)[4][2])
{
    __builtin_amdgcn_s_setprio(1);
#pragma unroll
    for (int h = 0; h < 2; ++h)
#pragma unroll
        for (int ii = 0; ii < 2; ++ii)
#pragma unroll
            for (int j = 0; j < 4; ++j)
                acc[2 * P + ii][j] = __builtin_amdgcn_mfma_f32_16x16x32_bf16(
                    af[ii][h], bfr[j][h], acc[2 * P + ii][j], 0, 0, 0);
    __builtin_amdgcn_s_setprio(0);
}

__device__ __forceinline__ void read_af(bf16x8 (&dst)[2][2], const __bf16* cA,
                                        int rowBase, int lm, int kq, int sw)
{
#pragma unroll
    for (int ii = 0; ii < 2; ++ii)
#pragma unroll
        for (int h = 0; h < 2; ++h)
            dst[ii][h] = *reinterpret_cast<const bf16x8*>(
                &cA[(rowBase + ii * 16 + lm) * BK2 + ((kq + h * 4) ^ sw) * 8]);
}

__device__ __forceinline__ void read_bf(bf16x8 (&dst)[4][2], const __bf16* cB,
                                        int wn, int lm, int kq, int sw)
{
#pragma unroll
    for (int j = 0; j < 4; ++j)
#pragma unroll
        for (int h = 0; h < 2; ++h)
            dst[j][h] = *reinterpret_cast<const bf16x8*>(
                &cB[(wn + j * 16 + lm) * BK2 + ((kq + h * 4) ^ sw) * 8]);
}

__global__ __launch_bounds__(512)
void gemm_bf16_bt_pipe(const __bf16* __restrict__ A, const __bf16* __restrict__ B,
                       const float* __restrict__ scale, const float* __restrict__ bias,
                       float* __restrict__ Out, int M, int N, int K)
{
    __shared__ __bf16 sA[2][BM2 * BK2];   // 64 KB
    __shared__ __bf16 sB[2][BN2 * BK2];   // 64 KB

    const int tid  = threadIdx.x;
    const int wave = tid >> 6;
    const int lane = tid & 63;
    const int row0 = blockIdx.y * BM2;
    const int col0 = blockIdx.x * BN2;

    // staging: one call = 512thr x 16B = 8KB = one 64-row quarter.
    // LDS[row][blk] = G[row][blk ^ (row&7)]  (linear dest, pre-swizzled src).
    const int sRow = lane >> 3;
    const int gBlk = (lane & 7) ^ sRow;
    const size_t aBase = (size_t)(row0 + wave * 8 + sRow) * K + gBlk * 8;
    const size_t bBase = (size_t)(col0 + wave * 8 + sRow) * K + gBlk * 8;
    const int ldsWOff = wave * 8 * BK2;

#define STAGE_A(buf, q, kt_) \
    __builtin_amdgcn_global_load_lds( \
        (const AS1 void*)(A + aBase + (size_t)(q) * 64 * K + (size_t)(kt_) * BK2), \
        (AS3 void*)&sA[(buf)][(q) * 64 * BK2 + ldsWOff], 16, 0, 0)
#define STAGE_B(buf, q, kt_) \
    __builtin_amdgcn_global_load_lds( \
        (const AS1 void*)(B + bBase + (size_t)(q) * 64 * K + (size_t)(kt_) * BK2), \
        (AS3 void*)&sB[(buf)][(q) * 64 * BK2 + ldsWOff], 16, 0, 0)

    // fragment geometry
    const int wm = (wave >> 2) * 128;
    const int wn = (wave & 3) * 64;
    const int lm = lane & 15;
    const int kq = lane >> 4;
    const int sw = lm & 7;

    floatx4 acc[8][4];
#pragma unroll
    for (int i = 0; i < 8; ++i)
#pragma unroll
        for (int j = 0; j < 4; ++j)
            acc[i][j] = (floatx4)0.0f;

    bf16x8 bfr[4][2];      // current tile's B fragments
    bf16x8 afE[2][2];      // A fragments for even phases (P0, P2)
    bf16x8 afO[2][2];      // A fragments for odd phases (P1, P3)
    const int nt = K / BK2;   // launcher guarantees even, >= 4

    // --- prologue. Issue order matches steady FIFO so vmcnt counts stay
    // uniform. Leaves outstanding: [A(0)q1q3][B(1)][A(1)q0q2] = 8.
    STAGE_A(0, 0, 0); STAGE_A(0, 2, 0);                              // A(0)q0q2
    STAGE_B(0, 0, 0); STAGE_B(0, 1, 0); STAGE_B(0, 2, 0); STAGE_B(0, 3, 0);
    STAGE_A(0, 1, 0); STAGE_A(0, 3, 0);                              // A(0)q1q3
    STAGE_B(1, 0, 1); STAGE_B(1, 1, 1); STAGE_B(1, 2, 1); STAGE_B(1, 3, 1);
    STAGE_A(1, 0, 1); STAGE_A(1, 2, 1);                              // A(1)q0q2
    asm volatile("s_waitcnt vmcnt(8)" ::: "memory");   // drains A(0)q0q2 + B(0)
    BARRIER();
    read_bf(bfr, sB[0], wn, lm, kq, sw);
    read_af(afE, sA[0], wm, lm, kq, sw);

#define TILE(c, n1, n2)                                                        \
    /* P0 */                                                                   \
    STAGE_A((c) ^ 1, 1, n1); STAGE_A((c) ^ 1, 3, n1);                          \
    mfma_cluster<0>(acc, afE, bfr);                                            \
    read_af(afO, sA[(c)], wm + 32, lm, kq, sw);                                \
    asm volatile("s_waitcnt vmcnt(8)" ::: "memory");                           \
    BARRIER();                                                                 \
    /* P1 */                                                                   \
    STAGE_B((c), 0, n2); STAGE_B((c), 1, n2);                                  \
    STAGE_B((c), 2, n2); STAGE_B((c), 3, n2);                                  \
    mfma_cluster<1>(acc, afO, bfr);                                            \
    read_af(afE, sA[(c)], wm + 64, lm, kq, sw);                                \
    BARRIER();                                                                 \
    /* P2 */                                                                   \
    STAGE_A((c), 0, n2); STAGE_A((c), 2, n2);                                  \
    mfma_cluster<2>(acc, afE, bfr);                                            \
    read_af(afO, sA[(c)], wm + 96, lm, kq, sw);                                \
    asm volatile("s_waitcnt vmcnt(8)" ::: "memory");                           \
    BARRIER();                                                                 \
    /* P3 */                                                                   \
    mfma_cluster<3>(acc, afO, bfr);                                            \
    read_bf(bfr, sB[(c) ^ 1], wn, lm, kq, sw);                                 \
    read_af(afE, sA[(c) ^ 1], wm, lm, kq, sw);                                 \
    BARRIER();

    for (int it = 0; it < nt / 2; ++it) {
        const int kt = 2 * it;
        const int e1 = kt + 1;                        // real
        const int e2 = (kt + 2 < nt) ? kt + 2 : 0;    // phantoms keep FIFO uniform
        const int o2 = (kt + 3 < nt) ? kt + 3 : 0;
        TILE(0, e1, e2)
        TILE(1, e2, o2)
    }
    asm volatile("s_waitcnt vmcnt(0)" ::: "memory");  // drain phantoms before exit
#undef TILE
#undef STAGE_A
#undef STAGE_B

    // --- epilogue: C/D layout col=lane&15, row=(lane>>4)*4+reg (m89-verified)
#pragma unroll
    for (int j = 0; j < 4; ++j) {
        int n = col0 + wn + j * 16 + lm;
        float sc = scale[n];
        float bi = bias[n];
#pragma unroll
        for (int i = 0; i < 8; ++i) {
#pragma unroll
            for (int r = 0; r < 4; ++r) {
                int m = row0 + wm + i * 16 + kq * 4 + r;
                Out[(size_t)m * N + n] = sc * acc[i][j][r] + bi;
            }
        }
    }
}

// ---------------------------------------------------------------------------
// GEMM fallback: 128x128 tile, BK=64, m97 structure.
// ---------------------------------------------------------------------------
#define BM 128
#define BN 128
#define BK 64

__global__ __launch_bounds__(256)
void gemm_bf16_bt(const __bf16* __restrict__ A, const __bf16* __restrict__ B,
                  const float* __restrict__ scale, const float* __restrict__ bias,
                  float* __restrict__ Out, int M, int N, int K)
{
    __shared__ __bf16 sA[BM * BK];
    __shared__ __bf16 sB[BN * BK];

    const int tid  = threadIdx.x;
    const int row0 = blockIdx.y * BM;
    const int col0 = blockIdx.x * BN;
    const int wave = tid >> 6;
    const int lane = tid & 63;

    const int sRow = lane >> 3;
    const int gBlk = (lane & 7) ^ sRow;
    size_t aOff[4], bOff[4];
    const __bf16* ldsA[4];
    const __bf16* ldsB[4];
#pragma unroll
    for (int q = 0; q < 4; ++q) {
        int r = wave * 32 + q * 8 + sRow;
        aOff[q] = (size_t)(row0 + r) * K + gBlk * 8;
        bOff[q] = (size_t)(col0 + r) * K + gBlk * 8;
        ldsA[q] = &sA[(wave * 32 + q * 8) * BK];
        ldsB[q] = &sB[(wave * 32 + q * 8) * BK];
    }

    const int wm = (wave >> 1) * 64;
    const int wn = (wave & 1) * 64;
    const int lm = lane & 15;
    const int kq = lane >> 4;
    const int sw = lm & 7;

    floatx4 acc[4][4];
#pragma unroll
    for (int i = 0; i < 4; ++i)
#pragma unroll
        for (int j = 0; j < 4; ++j)
            acc[i][j] = (floatx4)0.0f;

    for (int k0 = 0; k0 < K; k0 += BK) {
#pragma unroll
        for (int q = 0; q < 4; ++q) {
            __builtin_amdgcn_global_load_lds((const AS1 void*)(A + aOff[q] + k0),
                                             (AS3 void*)ldsA[q], 16, 0, 0);
            __builtin_amdgcn_global_load_lds((const AS1 void*)(B + bOff[q] + k0),
                                             (AS3 void*)ldsB[q], 16, 0, 0);
        }
        __syncthreads();

#pragma unroll
        for (int h = 0; h < 2; ++h) {
            const int blkA = (kq + h * 4);
            bf16x8 af[4], bfr[4];
#pragma unroll
            for (int i = 0; i < 4; ++i) {
                int row = wm + i * 16 + lm;
                af[i] = *reinterpret_cast<const bf16x8*>(
                            &sA[row * BK + (blkA ^ sw) * 8]);
            }
#pragma unroll
            for (int j = 0; j < 4; ++j) {
                int row = wn + j * 16 + lm;
                bfr[j] = *reinterpret_cast<const bf16x8*>(
                            &sB[row * BK + (blkA ^ sw) * 8]);
            }
#pragma unroll
            for (int i = 0; i < 4; ++i)
#pragma unroll
                for (int j = 0; j < 4; ++j)
                    acc[i][j] = __builtin_amdgcn_mfma_f32_16x16x32_bf16(
                                    af[i], bfr[j], acc[i][j], 0, 0, 0);
        }
        __syncthreads();
    }

#pragma unroll
    for (int j = 0; j < 4; ++j) {
        int n = col0 + wn + j * 16 + lm;
        float sc = scale[n];
        float bi = bias[n];
#pragma unroll
        for (int i = 0; i < 4; ++i) {
#pragma unroll
            for (int r = 0; r < 4; ++r) {
                int m = row0 + wm + i * 16 + kq * 4 + r;
                Out[(size_t)m * N + n] = sc * acc[i][j][r] + bi;
            }
        }
    }
}

// ---------------------------------------------------------------------------
// Fallback: fused conversion in staging, no workspace needed.
// ---------------------------------------------------------------------------
__global__ __launch_bounds__(256)
void fp4linear_gemm(const float* __restrict__ X, const int* __restrict__ W,
                    const float* __restrict__ scale, const float* __restrict__ bias,
                    float* __restrict__ Out, int M, int N, int K)
{
    __shared__ __bf16 sA[BM * 32];
    __shared__ __bf16 sB[BN * 32];

    const int tid  = threadIdx.x;
    const int row0 = blockIdx.y * BM;
    const int col0 = blockIdx.x * BN;
    const int wave = tid >> 6;
    const int lane = tid & 63;
    const int wm = (wave >> 1) * 64;
    const int wn = (wave & 1) * 64;
    const int lm = lane & 15;
    const int kq = lane >> 4;

    floatx4 acc[4][4];
#pragma unroll
    for (int i = 0; i < 4; ++i)
#pragma unroll
        for (int j = 0; j < 4; ++j)
            acc[i][j] = (floatx4)0.0f;

    for (int k0 = 0; k0 < K; k0 += 32) {
        float4 fa[4];
        int4   ib[4];
#pragma unroll
        for (int l = 0; l < 4; ++l) {
            int idx = tid + l * 256;
            int r = idx >> 3, c4 = idx & 7;
            fa[l] = *reinterpret_cast<const float4*>(
                        &X[(size_t)(row0 + r) * K + k0 + c4 * 4]);
        }
#pragma unroll
        for (int l = 0; l < 4; ++l) {
            int idx = tid + l * 256;
            int r = idx >> 3, c4 = idx & 7;
            ib[l] = *reinterpret_cast<const int4*>(
                        &W[(size_t)(col0 + r) * K + k0 + c4 * 4]);
        }
        __syncthreads();
#pragma unroll
        for (int l = 0; l < 4; ++l) {
            int idx = tid + l * 256;
            int r = idx >> 3, c4 = idx & 7;
            bf16x4 h;
            h[0] = (__bf16)fa[l].x; h[1] = (__bf16)fa[l].y;
            h[2] = (__bf16)fa[l].z; h[3] = (__bf16)fa[l].w;
            *reinterpret_cast<bf16x4*>(&sA[r * 32 + c4 * 4]) = h;
        }
#pragma unroll
        for (int l = 0; l < 4; ++l) {
            int idx = tid + l * 256;
            int r = idx >> 3, c4 = idx & 7;
            bf16x4 h;
            h[0] = (__bf16)(float)ib[l].x; h[1] = (__bf16)(float)ib[l].y;
            h[2] = (__bf16)(float)ib[l].z; h[3] = (__bf16)(float)ib[l].w;
            *reinterpret_cast<bf16x4*>(&sB[r * 32 + c4 * 4]) = h;
        }
        __syncthreads();

        bf16x8 af[4], bfr[4];
#pragma unroll
        for (int i = 0; i < 4; ++i)
            af[i] = *reinterpret_cast<const bf16x8*>(
                        &sA[(wm + i * 16 + lm) * 32 + kq * 8]);
#pragma unroll
        for (int j = 0; j < 4; ++j)
            bfr[j] = *reinterpret_cast<const bf16x8*>(
                        &sB[(wn + j * 16 + lm) * 32 + kq * 8]);
#pragma unroll
        for (int i = 0; i < 4; ++i)
#pragma unroll
            for (int j = 0; j < 4; ++j)
                acc[i][j] = __builtin_amdgcn_mfma_f32_16x16x32_bf16(
                                af[i], bfr[j], acc[i][j], 0, 0, 0);
    }

#pragma unroll
    for (int j = 0; j < 4; ++j) {
        int n = col0 + wn + j * 16 + lm;
        float sc = scale[n];
        float bi = bias[n];
#pragma unroll
        for (int i = 0; i < 4; ++i) {
#pragma unroll
            for (int r = 0; r < 4; ++r) {
                int m = row0 + wm + i * 16 + kq * 4 + r;
                Out[(size_t)m * N + n] = sc * acc[i][j][r] + bi;
            }
        }
    }
}

extern "C" void kernel_launch(void* const* d_in, const int* in_sizes, int n_in,
                              void* d_out, int out_size, void* d_ws, size_t ws_size,
                              hipStream_t stream) {
    const float* x     = (const float*)d_in[0];
    const int*   wq    = (const int*)d_in[1];
    const float* scale = (const float*)d_in[2];
    const float* bias  = (const float*)d_in[3];
    float* out = (float*)d_out;

    const int N = in_sizes[2];            // OUT = 4096
    const int K = in_sizes[1] / N;        // IN  = 4096
    const int M = in_sizes[0] / K;        // B*S = 8192

    const size_t xElems = (size_t)M * K;
    const size_t wElems = (size_t)N * K;
    const size_t need   = (xElems + wElems) * sizeof(__bf16);

    const bool cvt_ok = (ws_size >= need) && (xElems % 8 == 0) && (wElems % 8 == 0);
    const int  nt     = K / BK2;

    if (cvt_ok) {
        __bf16* xb = (__bf16*)d_ws;
        __bf16* wb = xb + xElems;
        int nx8 = (int)(xElems / 8);
        int nw8 = (int)(wElems / 8);
        int total = nx8 + nw8;
        int cvtBlocks = (total + 255) / 256;
        if (cvtBlocks > 2048) cvtBlocks = 2048;
        hipLaunchKernelGGL(cvt_both8, dim3(cvtBlocks), dim3(256), 0, stream,
                           x, wq, xb, wb, nx8, nw8);
        if ((M % BM2 == 0) && (N % BN2 == 0) && (K % BK2 == 0) &&
            (nt % 2 == 0) && (nt >= 4)) {
            hipLaunchKernelGGL(gemm_bf16_bt_pipe, dim3(N / BN2, M / BM2), dim3(512),
                               0, stream, xb, wb, scale, bias, out, M, N, K);
        } else if ((M % BM == 0) && (N % BN == 0) && (K % BK == 0)) {
            hipLaunchKernelGGL(gemm_bf16_bt, dim3(N / BN, M / BM), dim3(256),
                               0, stream, xb, wb, scale, bias, out, M, N, K);
        } else {
            hipLaunchKernelGGL(fp4linear_gemm, dim3(N / BN, M / BM), dim3(256),
                               0, stream, x, wq, scale, bias, out, M, N, K);
        }
    } else {
        hipLaunchKernelGGL(fp4linear_gemm, dim3(N / BN, M / BM), dim3(256), 0, stream,
                           x, wq, scale, bias, out, M, N, K);
    }
}